// Round 5
// baseline (294.058 us; speedup 1.0000x reference)
//
#include <hip/hip_runtime.h>

// CLIPAttention (ShareKey, layer>=9): softmax(scores+bias)==softmax(bias) => q path dead.
// Pipeline (fp16 intermediates, fp32 accum):
//   prep_all: hs->f16 [16][584][1024]; v_w/out_w->f16; P[h][i][j] softmax -> f16 [16][640][608]
//   GEMM1 (MODE0): VT[e][b*584+s] = sum_k vw[e,k]*hs[b,s,k] + v_b[e]          (f16)
//   PV    (MODE1): per head h: C[i][(b,d)] = sum_j P[h,i,j]*VT[h*64+d][b*584+j] -> out_h
//   GEMM4 (MODE2): out[m][e] = sum_k out_h[m,k]*ow[e,k] + out_b[e]            (f32)
// GEMMs: 64x128 tile, 4 waves, BK=32, global_load_lds(16B) with PER-LANE pre-swizzled
// global source -> LDS [kgroup][row][16B-chunk] layout (conflict-free ds_read_b128),
// double-buffered (1 barrier/K-step), bijective XCD-chunk swizzle.

typedef __attribute__((ext_vector_type(4))) float f32x4;
typedef __attribute__((ext_vector_type(4))) unsigned int u32x4;

__device__ __forceinline__ unsigned short f2h(float f) {
  union { _Float16 h; unsigned short u; } x;
  x.h = (_Float16)f;
  return x.u;
}

__device__ __forceinline__ void mfma16(f32x4& d, u32x4 a, u32x4 b) {
  asm("v_mfma_f32_16x16x32_f16 %0, %1, %2, %0" : "+v"(d) : "v"(a), "v"(b));
}

__device__ __forceinline__ void gl_lds16(const unsigned short* g, unsigned short* l) {
  __builtin_amdgcn_global_load_lds(
      (const __attribute__((address_space(1))) unsigned int*)g,
      (__attribute__((address_space(3))) unsigned int*)l, 16, 0, 0);
}

// ---------------- fused prep: hs->f16, weights->f16, bias softmax ----------------
__global__ __launch_bounds__(256) void prep_all_kernel(
    const float* __restrict__ HS, const float* __restrict__ VW,
    const float* __restrict__ OW, const float* __restrict__ SB,
    unsigned short* __restrict__ hsY, unsigned short* __restrict__ vwY,
    unsigned short* __restrict__ owY, unsigned short* __restrict__ P)
{
  __shared__ float buf[577];
  __shared__ float redm[4];
  __shared__ float reds[4];
  const int bid = blockIdx.x;
  const int tid = threadIdx.x;

  if (bid < 9344) {                       // hs convert, [16][584][1024] zero-padded
    const int row = bid;                  // b*584 + s
    const int b = row / 584;
    const int s = row - b * 584;
    const int col = tid << 2;
    ushort4 o = {0, 0, 0, 0};
    if (s < 577) {
      const float4 v = *(const float4*)(HS + (((size_t)(b * 577 + s)) << 10) + col);
      o.x = f2h(v.x); o.y = f2h(v.y); o.z = f2h(v.z); o.w = f2h(v.w);
    }
    *(ushort4*)(hsY + ((size_t)row << 10) + col) = o;
    return;
  }
  if (bid < 11392) {                      // weight convert (vw then ow)
    const int r = bid - 9344;
    const float* X = (r < 1024) ? VW : OW;
    unsigned short* Y = (r < 1024) ? vwY : owY;
    const int n = ((r & 1023) << 10) + (tid << 2);
    const float4 v = *(const float4*)(X + n);
    ushort4 o; o.x = f2h(v.x); o.y = f2h(v.y); o.z = f2h(v.z); o.w = f2h(v.w);
    *(ushort4*)(Y + n) = o;
    return;
  }
  // softmax rows: P[h][i][:] over 608 cols (577 live)
  const int r = bid - 11392;              // 0..10239
  const int h = r / 640;
  const int i = r - h * 640;
  unsigned short* prow = P + ((size_t)h * 640 + i) * 608;
  if (i >= 577) {
    for (int j = tid; j < 608; j += 256) prow[j] = 0;
    return;
  }
  const float* row = SB + ((size_t)h * 577 + i) * 577;
  float lmax = -3.0e38f;
  for (int j = tid; j < 577; j += 256) { float v = row[j]; buf[j] = v; lmax = fmaxf(lmax, v); }
  #pragma unroll
  for (int off = 32; off > 0; off >>= 1) lmax = fmaxf(lmax, __shfl_xor(lmax, off));
  if ((tid & 63) == 0) redm[tid >> 6] = lmax;
  __syncthreads();
  const float m = fmaxf(fmaxf(redm[0], redm[1]), fmaxf(redm[2], redm[3]));
  float lsum = 0.f;
  for (int j = tid; j < 577; j += 256) { float e = __expf(buf[j] - m); buf[j] = e; lsum += e; }
  #pragma unroll
  for (int off = 32; off > 0; off >>= 1) lsum += __shfl_xor(lsum, off);
  if ((tid & 63) == 0) reds[tid >> 6] = lsum;
  __syncthreads();
  const float inv = 1.f / (reds[0] + reds[1] + reds[2] + reds[3]);
  for (int j = tid; j < 608; j += 256)
    prow[j] = (j < 577) ? f2h(buf[j] * inv) : (unsigned short)0;
}

// ---------------- unified 64x128 BT-GEMM, k-chunk LDS layout, dbuf, XCD swizzle ----------------
// C[m,n] = sum_k A[m,k] * B[n,k] (+bias). MODE: 0=GEMM1, 1=PV, 2=GEMM4. 1D grid.
// LDS layout: tile stored as [kgroup=4][rows][8 shorts]; chunk c=(kg*R + row) at shorts c*8.
// Wave w stages kgroup w: lane l loads global row (r0+l), k-slice [k0+w*8, +8).
template<int MODE>
__global__ __launch_bounds__(256) void gemm64_kernel(
    const unsigned short* __restrict__ A, int lda,
    const unsigned short* __restrict__ B, int ldb,
    const float* __restrict__ bias,
    void* __restrict__ Cv, int ldc, int K)
{
  __shared__ unsigned short As0[64 * 32];    // 4KB: [4][64][8]
  __shared__ unsigned short Bs0[128 * 32];   // 8KB: [4][128][8]
  __shared__ unsigned short As1[64 * 32];
  __shared__ unsigned short Bs1[128 * 32];
  const int tid  = threadIdx.x;
  const int lane = tid & 63;
  const int w    = tid >> 6;
  const int l15 = lane & 15, lhi = lane >> 4;

  // bijective XCD-chunk swizzle (gridDim.x % 8 == 0)
  const int nwg8 = (int)gridDim.x >> 3;
  const int orig = blockIdx.x;
  const int id = (orig & 7) * nwg8 + (orig >> 3);
  int mt, nt, hh = 0;
  if (MODE == 1)      { hh = id / 80; const int r = id - hh * 80; mt = r % 10; nt = r / 10; }
  else if (MODE == 0) { mt = id & 15; nt = id >> 4; }   // 16 ids share one B-tile
  else                { nt = id & 7;  mt = id >> 3; }   // 8 ids share one A-tile
  const int m0 = mt * 64, n0 = nt * 128;

  // per-lane global pointers (pre-swizzled source for the k-chunk LDS layout)
  const unsigned short* Abase = (MODE == 1) ? A + (size_t)hh * 640 * 608 : A;
  const unsigned short* gA = Abase + (size_t)(m0 + lane) * lda + w * 8;
  const unsigned short* gB0;
  const unsigned short* gB1;
  if (MODE == 1) {
    const int nb0 = n0 + lane, nb1 = n0 + 64 + lane;
    gB0 = B + (size_t)(hh * 64 + (nb0 & 63)) * 9344 + (nb0 >> 6) * 584 + w * 8;
    gB1 = B + (size_t)(hh * 64 + (nb1 & 63)) * 9344 + (nb1 >> 6) * 584 + w * 8;
  } else {
    gB0 = B + (size_t)(n0 + lane) * ldb + w * 8;
    gB1 = gB0 + (size_t)64 * ldb;
  }

  f32x4 acc[4][2] = {};
  const int NT = K >> 5;

#define STAGE(AS, BS, k0)                       \
  do {                                          \
    gl_lds16(gA + (k0), (AS) + w * 512);        \
    gl_lds16(gB0 + (k0), (BS) + w * 1024);      \
    gl_lds16(gB1 + (k0), (BS) + w * 1024 + 512);\
  } while (0)

#define COMPUTE(AS, BS)                                                  \
  do {                                                                   \
    u32x4 af[4], bv[2];                                                  \
    _Pragma("unroll")                                                    \
    for (int i = 0; i < 4; i++)                                          \
      af[i] = *(const u32x4*)&(AS)[(lhi * 64 + i * 16 + l15) * 8];       \
    _Pragma("unroll")                                                    \
    for (int j = 0; j < 2; j++)                                          \
      bv[j] = *(const u32x4*)&(BS)[(lhi * 128 + w * 32 + j * 16 + l15) * 8];\
    _Pragma("unroll")                                                    \
    for (int i = 0; i < 4; i++)                                          \
      _Pragma("unroll")                                                  \
      for (int j = 0; j < 2; j++)                                        \
        mfma16(acc[i][j], af[i], bv[j]);                                 \
  } while (0)

  STAGE(As0, Bs0, 0);
  __syncthreads();
  for (int kt = 0; kt < NT; kt += 2) {
    if (kt + 1 < NT) STAGE(As1, Bs1, (kt + 1) << 5);
    COMPUTE(As0, Bs0);
    __syncthreads();
    if (kt + 1 < NT) {
      if (kt + 2 < NT) STAGE(As0, Bs0, (kt + 2) << 5);
      COMPUTE(As1, Bs1);
      __syncthreads();
    }
  }
#undef STAGE
#undef COMPUTE

  #pragma unroll
  for (int i = 0; i < 4; i++) {
    #pragma unroll
    for (int r = 0; r < 4; r++) {
      const int row = m0 + i * 16 + (lhi << 2) + r;
      if (MODE == 0) {
        const float rbias = bias[row];
        #pragma unroll
        for (int j = 0; j < 2; j++) {
          const int col = n0 + w * 32 + j * 16 + l15;
          ((unsigned short*)Cv)[(size_t)row * ldc + col] = f2h(acc[i][j][r] + rbias);
        }
      } else if (MODE == 1) {
        if (row < 577) {
          #pragma unroll
          for (int j = 0; j < 2; j++) {
            const int n = n0 + w * 32 + j * 16 + l15;
            const int b = n >> 6, d = n & 63;
            ((unsigned short*)Cv)[(((size_t)b * 577 + row) << 10) + hh * 64 + d] =
                f2h(acc[i][j][r]);
          }
        }
      } else {
        if (row < 9232) {
          #pragma unroll
          for (int j = 0; j < 2; j++) {
            const int col = n0 + w * 32 + j * 16 + l15;
            ((float*)Cv)[(size_t)row * ldc + col] = acc[i][j][r] + bias[col];
          }
        }
      }
    }
  }
}

extern "C" void kernel_launch(void* const* d_in, const int* in_sizes, int n_in,
                              void* d_out, int out_size, void* d_ws, size_t ws_size,
                              hipStream_t stream) {
  (void)in_sizes; (void)n_in; (void)out_size; (void)ws_size;
  const float* hs    = (const float*)d_in[0];
  const float* v_w   = (const float*)d_in[3];
  const float* v_b   = (const float*)d_in[4];
  const float* out_w = (const float*)d_in[5];
  const float* out_b = (const float*)d_in[6];
  const float* sb    = (const float*)d_in[8];
  float* out = (float*)d_out;

  char* ws = (char*)d_ws;
  constexpr size_t HS_SZ = (size_t)9344 * 1024 * 2;        // f16 hs; later reused as out_h
  constexpr size_t W_SZ  = (size_t)1024 * 1024 * 2;
  constexpr size_t VT_SZ = (size_t)1024 * 9344 * 2 + 256;  // + slack for b=15 K-tail reads
  unsigned short* hs_f16 = (unsigned short*)(ws);
  unsigned short* vw_f16 = (unsigned short*)(ws + HS_SZ);
  unsigned short* ow_f16 = (unsigned short*)(ws + HS_SZ + W_SZ);
  unsigned short* vt     = (unsigned short*)(ws + HS_SZ + 2 * W_SZ);
  unsigned short* pmat   = (unsigned short*)(ws + HS_SZ + 2 * W_SZ + VT_SZ);

  // 9344 hs blocks + 2048 weight blocks + 10240 softmax rows
  prep_all_kernel<<<21632, 256, 0, stream>>>(hs, v_w, out_w, sb,
                                             hs_f16, vw_f16, ow_f16, pmat);
  // GEMM1: VT[e][nn] = vw[e,:]·hs[nn,:] + v_b[e]; M=1024(16 tiles), N=9344(73), K=1024
  gemm64_kernel<0><<<1168, 256, 0, stream>>>(vw_f16, 1024, hs_f16, 1024, v_b,
                                             (void*)vt, 9344, 1024);
  // PV per head: M=640(10 tiles), N=1024(8), K=608; out_h -> hs_f16 buffer
  gemm64_kernel<1><<<1280, 256, 0, stream>>>(pmat, 608, vt, 0, nullptr,
                                             (void*)hs_f16, 0, 608);
  // GEMM4: out[m][e] = out_h[m,:]·ow[e,:] + out_b[e]; M=9344(146, store<9232), N=1024(8)
  gemm64_kernel<2><<<1168, 256, 0, stream>>>(hs_f16, 1024, ow_f16, 1024, out_b,
                                             (void*)out, 1024, 1024);
}

// Round 6
// 213.684 us; speedup vs baseline: 1.3761x; 1.3761x over previous
//
#include <hip/hip_runtime.h>

// CLIPAttention (ShareKey, layer>=9): softmax(scores+bias)==softmax(bias) => q path dead.
// Pipeline (fp16 intermediates, fp32 accum):
//   prep_all: hs->f16 [16][584][1024]; v_w/out_w->f16; P softmax -> f16 [16][640][608]
//   GEMM1 (MODE0): VT[e][b*584+s] = sum_k vw[e,k]*hs[b,s,k] + v_b[e]          (f16)
//   PV    (MODE1): per head h: C[i][(b,d)] = sum_j P[h,i,j]*VT[h*64+d][b*584+j] -> out_h
//   GEMM4 (MODE2): out[m][e] = sum_k out_h[m,k]*ow[e,k] + out_b[e]            (f32)
// GEMMs: 128x128 tile, TWO waves (each owns 128x64: af[8] x bv[4], 32 MFMA/K-step
// -> 375B LDS-read per MFMA vs 512B at 4-wave, attacking the LDS-BW ceiling),
// BK=32, coalesced global_load_lds(16B) staging (wave0=A, wave1=B, 16 rows x 64B
// per call), double-buffered LDS (1 barrier/K-step), bijective XCD-chunk swizzle.

typedef __attribute__((ext_vector_type(4))) float f32x4;
typedef __attribute__((ext_vector_type(4))) unsigned int u32x4;

__device__ __forceinline__ unsigned short f2h(float f) {
  union { _Float16 h; unsigned short u; } x;
  x.h = (_Float16)f;
  return x.u;
}

__device__ __forceinline__ void mfma16(f32x4& d, u32x4 a, u32x4 b) {
  asm("v_mfma_f32_16x16x32_f16 %0, %1, %2, %0" : "+v"(d) : "v"(a), "v"(b));
}

__device__ __forceinline__ void gl_lds16(const unsigned short* g, unsigned short* l) {
  __builtin_amdgcn_global_load_lds(
      (const __attribute__((address_space(1))) unsigned int*)g,
      (__attribute__((address_space(3))) unsigned int*)l, 16, 0, 0);
}

// ---------------- fused prep: hs->f16, weights->f16, bias softmax ----------------
__global__ __launch_bounds__(256) void prep_all_kernel(
    const float* __restrict__ HS, const float* __restrict__ VW,
    const float* __restrict__ OW, const float* __restrict__ SB,
    unsigned short* __restrict__ hsY, unsigned short* __restrict__ vwY,
    unsigned short* __restrict__ owY, unsigned short* __restrict__ P)
{
  __shared__ float buf[577];
  __shared__ float redm[4];
  __shared__ float reds[4];
  const int bid = blockIdx.x;
  const int tid = threadIdx.x;

  if (bid < 9344) {                       // hs convert, [16][584][1024] zero-padded
    const int row = bid;                  // b*584 + s
    const int b = row / 584;
    const int s = row - b * 584;
    const int col = tid << 2;
    ushort4 o = {0, 0, 0, 0};
    if (s < 577) {
      const float4 v = *(const float4*)(HS + (((size_t)(b * 577 + s)) << 10) + col);
      o.x = f2h(v.x); o.y = f2h(v.y); o.z = f2h(v.z); o.w = f2h(v.w);
    }
    *(ushort4*)(hsY + ((size_t)row << 10) + col) = o;
    return;
  }
  if (bid < 11392) {                      // weight convert (vw then ow)
    const int r = bid - 9344;
    const float* X = (r < 1024) ? VW : OW;
    unsigned short* Y = (r < 1024) ? vwY : owY;
    const int n = ((r & 1023) << 10) + (tid << 2);
    const float4 v = *(const float4*)(X + n);
    ushort4 o; o.x = f2h(v.x); o.y = f2h(v.y); o.z = f2h(v.z); o.w = f2h(v.w);
    *(ushort4*)(Y + n) = o;
    return;
  }
  // softmax rows: P[h][i][:] over 608 cols (577 live)
  const int r = bid - 11392;              // 0..10239
  const int h = r / 640;
  const int i = r - h * 640;
  unsigned short* prow = P + ((size_t)h * 640 + i) * 608;
  if (i >= 577) {
    for (int j = tid; j < 608; j += 256) prow[j] = 0;
    return;
  }
  const float* row = SB + ((size_t)h * 577 + i) * 577;
  float lmax = -3.0e38f;
  for (int j = tid; j < 577; j += 256) { float v = row[j]; buf[j] = v; lmax = fmaxf(lmax, v); }
  #pragma unroll
  for (int off = 32; off > 0; off >>= 1) lmax = fmaxf(lmax, __shfl_xor(lmax, off));
  if ((tid & 63) == 0) redm[tid >> 6] = lmax;
  __syncthreads();
  const float m = fmaxf(fmaxf(redm[0], redm[1]), fmaxf(redm[2], redm[3]));
  float lsum = 0.f;
  for (int j = tid; j < 577; j += 256) { float e = __expf(buf[j] - m); buf[j] = e; lsum += e; }
  #pragma unroll
  for (int off = 32; off > 0; off >>= 1) lsum += __shfl_xor(lsum, off);
  if ((tid & 63) == 0) reds[tid >> 6] = lsum;
  __syncthreads();
  const float inv = 1.f / (reds[0] + reds[1] + reds[2] + reds[3]);
  for (int j = tid; j < 608; j += 256)
    prow[j] = (j < 577) ? f2h(buf[j] * inv) : (unsigned short)0;
}

// ---------------- unified 128x128 BT-GEMM, 2 waves, dbuf LDS, XCD swizzle ----------------
// C[m,n] = sum_k A[m,k] * B[n,k] (+bias). MODE: 0=GEMM1, 1=PV, 2=GEMM4. 1D grid, 128 thr.
template<int MODE>
__global__ __launch_bounds__(128, 2) void gemm2w_kernel(
    const unsigned short* __restrict__ A, int lda,
    const unsigned short* __restrict__ B, int ldb,
    const float* __restrict__ bias,
    void* __restrict__ Cv, int ldc, int K)
{
  __shared__ unsigned short As0[128 * 32];   // 8KB each
  __shared__ unsigned short Bs0[128 * 32];
  __shared__ unsigned short As1[128 * 32];
  __shared__ unsigned short Bs1[128 * 32];
  const int tid  = threadIdx.x;
  const int lane = tid & 63;
  const int w    = tid >> 6;                 // 0: stages A, computes cols 0-63; 1: B, cols 64-127
  const int l15 = lane & 15, lhi = lane >> 4;
  const int lr = lane >> 2, lc = (lane & 3) << 3;   // staging: 4 lanes/row, 64B rows

  // bijective XCD-chunk swizzle (gridDim.x % 8 == 0)
  const int nwg8 = (int)gridDim.x >> 3;
  const int orig = blockIdx.x;
  const int id = (orig & 7) * nwg8 + (orig >> 3);
  int mt, nt, hh = 0;
  if (MODE == 1)      { hh = id / 40; const int r = id - hh * 40; nt = r & 7; mt = r >> 3; }
  else if (MODE == 0) { mt = id & 7;  nt = id >> 3; }   // 8 consecutive ids share B-tile
  else                { nt = id & 7;  mt = id >> 3; }   // 8 consecutive ids share A-tile
  const int m0 = mt * 128, n0 = nt * 128;

  // per-lane global pointers for this wave's operand (8 calls of 16 rows x 64B)
  const unsigned short* Abase = (MODE == 1) ? A + (size_t)hh * 640 * 608 : A;
  const unsigned short* g[8];
  if (w == 0) {
    #pragma unroll
    for (int c = 0; c < 8; c++)
      g[c] = Abase + (size_t)(m0 + c * 16 + lr) * lda + lc;
  } else {
    #pragma unroll
    for (int c = 0; c < 8; c++) {
      if (MODE == 1) {
        const int nb = n0 + c * 16 + lr;     // B row n -> VT[hh*64+(n&63)], col (n>>6)*584
        g[c] = B + (size_t)(hh * 64 + (nb & 63)) * 9344 + (nb >> 6) * 584 + lc;
      } else {
        g[c] = B + (size_t)(n0 + c * 16 + lr) * ldb + lc;
      }
    }
  }

  f32x4 acc[8][4] = {};
  const int NT = K >> 5;

#define STAGE(AS, BS, k0)                                  \
  do {                                                     \
    unsigned short* dst_ = (w == 0) ? (AS) : (BS);         \
    _Pragma("unroll")                                      \
    for (int c = 0; c < 8; c++)                            \
      gl_lds16(g[c] + (k0), dst_ + c * 512);               \
  } while (0)

#define COMPUTE(AS, BS)                                                        \
  do {                                                                         \
    u32x4 af[8], bv[4];                                                        \
    _Pragma("unroll")                                                          \
    for (int i = 0; i < 8; i++)                                                \
      af[i] = *(const u32x4*)&(AS)[(i * 16 + l15) * 32 + (lhi << 3)];          \
    _Pragma("unroll")                                                          \
    for (int j = 0; j < 4; j++)                                                \
      bv[j] = *(const u32x4*)&(BS)[(w * 64 + j * 16 + l15) * 32 + (lhi << 3)]; \
    _Pragma("unroll")                                                          \
    for (int i = 0; i < 8; i++)                                                \
      _Pragma("unroll")                                                        \
      for (int j = 0; j < 4; j++)                                              \
        mfma16(acc[i][j], af[i], bv[j]);                                       \
  } while (0)

  STAGE(As0, Bs0, 0);
  __syncthreads();
  for (int kt = 0; kt < NT; kt += 2) {
    if (kt + 1 < NT) STAGE(As1, Bs1, (kt + 1) << 5);   // issue next before compute
    COMPUTE(As0, Bs0);
    __syncthreads();
    if (kt + 1 < NT) {
      if (kt + 2 < NT) STAGE(As0, Bs0, (kt + 2) << 5);
      COMPUTE(As1, Bs1);
      __syncthreads();
    }
  }
#undef STAGE
#undef COMPUTE

  #pragma unroll
  for (int i = 0; i < 8; i++) {
    #pragma unroll
    for (int r = 0; r < 4; r++) {
      const int row = m0 + i * 16 + (lhi << 2) + r;
      if (MODE == 0) {
        const float rbias = bias[row];
        #pragma unroll
        for (int j = 0; j < 4; j++) {
          const int col = n0 + w * 64 + j * 16 + l15;
          ((unsigned short*)Cv)[(size_t)row * ldc + col] = f2h(acc[i][j][r] + rbias);
        }
      } else if (MODE == 1) {
        if (row < 577) {
          #pragma unroll
          for (int j = 0; j < 4; j++) {
            const int n = n0 + w * 64 + j * 16 + l15;
            const int b = n >> 6, d = n & 63;
            ((unsigned short*)Cv)[(((size_t)b * 577 + row) << 10) + hh * 64 + d] =
                f2h(acc[i][j][r]);
          }
        }
      } else {
        if (row < 9232) {
          #pragma unroll
          for (int j = 0; j < 4; j++) {
            const int col = n0 + w * 64 + j * 16 + l15;
            ((float*)Cv)[(size_t)row * ldc + col] = acc[i][j][r] + bias[col];
          }
        }
      }
    }
  }
}

extern "C" void kernel_launch(void* const* d_in, const int* in_sizes, int n_in,
                              void* d_out, int out_size, void* d_ws, size_t ws_size,
                              hipStream_t stream) {
  (void)in_sizes; (void)n_in; (void)out_size; (void)ws_size;
  const float* hs    = (const float*)d_in[0];
  const float* v_w   = (const float*)d_in[3];
  const float* v_b   = (const float*)d_in[4];
  const float* out_w = (const float*)d_in[5];
  const float* out_b = (const float*)d_in[6];
  const float* sb    = (const float*)d_in[8];
  float* out = (float*)d_out;

  char* ws = (char*)d_ws;
  constexpr size_t HS_SZ = (size_t)9344 * 1024 * 2;        // f16 hs; later reused as out_h
  constexpr size_t W_SZ  = (size_t)1024 * 1024 * 2;
  constexpr size_t VT_SZ = (size_t)1024 * 9344 * 2 + 256;  // + slack for b=15 K-tail reads
  unsigned short* hs_f16 = (unsigned short*)(ws);
  unsigned short* vw_f16 = (unsigned short*)(ws + HS_SZ);
  unsigned short* ow_f16 = (unsigned short*)(ws + HS_SZ + W_SZ);
  unsigned short* vt     = (unsigned short*)(ws + HS_SZ + 2 * W_SZ);
  unsigned short* pmat   = (unsigned short*)(ws + HS_SZ + 2 * W_SZ + VT_SZ);

  // 9344 hs blocks + 2048 weight blocks + 10240 softmax rows
  prep_all_kernel<<<21632, 256, 0, stream>>>(hs, v_w, out_w, sb,
                                             hs_f16, vw_f16, ow_f16, pmat);
  // GEMM1: VT[e][nn] = vw[e,:]·hs[nn,:] + v_b[e]; M=1024(8 tiles), N=9344(73), K=1024
  gemm2w_kernel<0><<<584, 128, 0, stream>>>(vw_f16, 1024, hs_f16, 1024, v_b,
                                            (void*)vt, 9344, 1024);
  // PV per head: M=640(5 tiles), N=1024(8), K=608; out_h -> hs_f16 buffer
  gemm2w_kernel<1><<<640, 128, 0, stream>>>(pmat, 608, vt, 0, nullptr,
                                            (void*)hs_f16, 0, 608);
  // GEMM4: out[m][e] = out_h[m,:]·ow[e,:] + out_b[e]; M=9344(73, store<9232), N=1024(8)
  gemm2w_kernel<2><<<584, 128, 0, stream>>>(hs_f16, 1024, ow_f16, 1024, out_b,
                                            (void*)out, 1024, 1024);
}